// Round 8
// baseline (2173.981 us; speedup 1.0000x reference)
//
#include <hip/hip_runtime.h>
#include <math.h>
#include <stdint.h>

#define NB 8
#define NN 1024
#define DD 256
#define NP1 1025
#define LDP 1028   // padded row stride for P0 in ws (16B-aligned rows)
#define NSTEPS 100

// ---------------------------------------------------------------- norms ----
__global__ __launch_bounds__(256) void norm_kernel(const float* __restrict__ fA,
                                                   const float* __restrict__ fB,
                                                   float* __restrict__ invA,
                                                   float* __restrict__ invB) {
  int gw = (blockIdx.x * 256 + threadIdx.x) >> 6;  // global wave id, 0..16383
  int lane = threadIdx.x & 63;
  const float* src;
  float* dst;
  int row;
  if (gw < NB * NN) { src = fA; dst = invA; row = gw; }
  else              { src = fB; dst = invB; row = gw - NB * NN; }
  float4 v = *(const float4*)(src + (size_t)row * DD + lane * 4);
  double ss = (double)v.x * v.x + (double)v.y * v.y + (double)v.z * v.z + (double)v.w * v.w;
#pragma unroll
  for (int o = 32; o; o >>= 1) ss += __shfl_xor(ss, o, 64);
  if (lane == 0) dst[row] = (float)(1.0 / sqrt(fmax(ss, 1e-12)));
}

// ------------------------------------------------ GEMM + exp + partial Z ---
__global__ __launch_bounds__(256) void gemm_exp_kernel(const float* __restrict__ fA,
                                                       const float* __restrict__ fB,
                                                       const float* __restrict__ invA,
                                                       const float* __restrict__ invB,
                                                       float* __restrict__ P0,
                                                       double* __restrict__ partZ) {
  const int id = blockIdx.x;
  const int b = id & 7;
  const int tile = id >> 3;
  const int bx = tile & 15, by = tile >> 4;
  const int row0 = by * 64, col0 = bx * 64;
  const int tid = threadIdx.x;
  const int tx = tid & 15, ty = tid >> 4;
  __shared__ __align__(16) float As[16][68];
  __shared__ __align__(16) float Bs[16][68];
  __shared__ double zred[256];
  float acc[4][4] = {{0.f}};
  const int lm = tid >> 2, kq = (tid & 3) << 2;
  const float sa = invA[b * NN + row0 + lm];
  const float sb = invB[b * NN + col0 + lm];
  const float* pA = fA + (size_t)(b * NN + row0 + lm) * DD + kq;
  const float* pB = fB + (size_t)(b * NN + col0 + lm) * DD + kq;
  for (int k0 = 0; k0 < DD; k0 += 16) {
    const float4 a4 = *(const float4*)(pA + k0);
    const float4 b4 = *(const float4*)(pB + k0);
    As[kq + 0][lm] = a4.x * sa; As[kq + 1][lm] = a4.y * sa;
    As[kq + 2][lm] = a4.z * sa; As[kq + 3][lm] = a4.w * sa;
    Bs[kq + 0][lm] = b4.x * sb; Bs[kq + 1][lm] = b4.y * sb;
    Bs[kq + 2][lm] = b4.z * sb; Bs[kq + 3][lm] = b4.w * sb;
    __syncthreads();
#pragma unroll
    for (int kk = 0; kk < 16; ++kk) {
      const float4 av = *(const float4*)&As[kk][ty * 4];
      const float4 bv = *(const float4*)&Bs[kk][tx * 4];
      const float ar[4] = {av.x, av.y, av.z, av.w};
      const float br[4] = {bv.x, bv.y, bv.z, bv.w};
#pragma unroll
      for (int a = 0; a < 4; ++a)
#pragma unroll
        for (int e = 0; e < 4; ++e)
          acc[a][e] = fmaf(ar[a], br[e], acc[a][e]);
    }
    __syncthreads();
  }
  double zs = 0.0;
#pragma unroll
  for (int a = 0; a < 4; ++a)
#pragma unroll
    for (int e = 0; e < 4; ++e) {
      const float S = acc[a][e];
      const float C = fminf(fmaxf(-S, -3.0f), 3.0f);
      const float p = expf(-5.0f * C);
      acc[a][e] = p;
      zs += (double)p;
    }
  {
    float* P0b = P0 + (size_t)b * NP1 * LDP;
#pragma unroll
    for (int a = 0; a < 4; ++a) {
      float4 v;
      v.x = acc[a][0]; v.y = acc[a][1]; v.z = acc[a][2]; v.w = acc[a][3];
      *(float4*)(P0b + (size_t)(row0 + ty * 4 + a) * LDP + col0 + tx * 4) = v;
    }
  }
  zred[tid] = zs;
  __syncthreads();
#pragma unroll
  for (int o = 128; o; o >>= 1) {
    if (tid < o) zred[tid] += zred[tid + o];
    __syncthreads();
  }
  if (tid == 0) partZ[(b * 16 + by) * 16 + bx] = zred[0];
}

// ------------------------------------------------------- dustbin borders ---
__global__ __launch_bounds__(1024) void fill_dustbin_kernel(const float* __restrict__ dustbin,
                                                            float* __restrict__ P0) {
  const int b = blockIdx.x, tid = threadIdx.x;
  const float d = dustbin[0];
  const float dv = expf(-5.0f * fminf(fmaxf(-d, -3.0f), 3.0f));
  float* P0b = P0 + (size_t)b * NP1 * LDP;
  for (int j = tid; j < NP1; j += 1024) {
    P0b[(size_t)NN * LDP + j] = dv;   // dustbin row
    P0b[(size_t)j * LDP + NN] = dv;   // dustbin col
  }
}

// --------------------------------------- init: rinit, zero B[0], zero ctr --
__global__ __launch_bounds__(256) void init2_kernel(const double* __restrict__ partZ,
                                                    float* __restrict__ rinit,
                                                    double* __restrict__ B0,
                                                    unsigned* __restrict__ ctr) {
  const int b = blockIdx.x, tid = threadIdx.x;
  __shared__ double red[256];
  red[tid] = partZ[b * 256 + tid];
  __syncthreads();
#pragma unroll
  for (int o = 128; o; o >>= 1) {
    if (tid < o) red[tid] += red[tid + o];
    __syncthreads();
  }
  if (tid == 0) rinit[b] = (float)(1.0 / red[0]);
  for (int j = tid; j < NP1; j += 256) B0[b * NP1 + j] = 0.0;
  for (int t = tid; t < NSTEPS; t += 256) ctr[t * 8 + b] = 0u;
}

// ------------------------------- persistent Sinkhorn (all 100 steps) -------
// 256 blocks x 512 thr, 1 block/CU (cooperative => co-resident).
// Block: batch b = id%8 (XCD pin), slab s = id/8 owns rows s*32..s*32+31,
// cached in LDS for the whole kernel. Per wave: 4 rows, r kept in registers.
// Cross-block state is atomics-only (B adds/loads, barrier counters) => no
// dirty-L2 coherence hazards; per-batch 32-arrival release/acquire barrier.
// Dustbin row (== dv everywhere) handled analytically by slab 31.
__global__ __launch_bounds__(512) void sinkhorn_persist(const float* __restrict__ P0,
                                                        const float* __restrict__ dustbin,
                                                        const float* __restrict__ rinit,
                                                        double* __restrict__ Bbuf,
                                                        unsigned* __restrict__ ctr,
                                                        float* __restrict__ rfin) {
  __shared__ __align__(16) float P0s[32][LDP];
  __shared__ __align__(16) float c_f[LDP];
  __shared__ __align__(16) float part[LDP];
  __shared__ double wred[8];
  __shared__ float rN_sh;

  const int id = blockIdx.x;
  const int b = id & 7;
  const int s = id >> 3;            // 0..31
  const int tid = threadIdx.x;
  const int lane = tid & 63;
  const int wv = tid >> 6;          // 0..7
  const int row0 = s * 32;
  const int wrow = wv * 4;          // local LDS row base for this wave
  const bool desig = (s == 31);     // handles dustbin row analytically

  const float d = dustbin[0];
  const float dv = expf(-5.0f * fminf(fmaxf(-d, -3.0f), 3.0f));

  // load the 32-row slab (incl. col N) into LDS: 8224 contiguous float4s
  {
    const float4* src = (const float4*)(P0 + ((size_t)b * NP1 + row0) * LDP);
    float4* dst = (float4*)&P0s[0][0];
    for (int idx = tid; idx < 32 * (LDP / 4); idx += 512) dst[idx] = src[idx];
  }
  const float rv0 = rinit[b];
  float r4[4] = {rv0, rv0, rv0, rv0};
  if (tid == 0) rN_sh = rv0;
  __syncthreads();

  for (int t = 0; t < NSTEPS; ++t) {
    double* Bacc = Bbuf + (size_t)(t % 3) * NB * NP1 + (size_t)b * NP1;
    // ---- c_t = ab / B_{t-1} (agent-scope atomic loads; t=0: c_0 = 1) ----
    if (t == 0) {
      for (int j = tid; j < LDP; j += 512) c_f[j] = 1.0f;
    } else {
      double* Bp = Bbuf + (size_t)((t + 2) % 3) * NB * NP1 + (size_t)b * NP1;
      for (int j = tid; j < NP1; j += 512) {
        const double bj = __hip_atomic_load(&Bp[j], __ATOMIC_RELAXED, __HIP_MEMORY_SCOPE_AGENT);
        c_f[j] = (float)(((j == NN) ? (double)NN : 1.0) / bj);
      }
      if (tid < 3) c_f[NP1 + tid] = 0.0f;
    }
    // ---- sum(c) in f64 (each thread sums exactly the c's it wrote) ----
    {
      double cs = (t == 0) ? ((tid == 0) ? 3.0 : 2.0)
                           : (double)c_f[tid] + (double)c_f[tid + 512] +
                             ((tid == 0) ? (double)c_f[1024] : 0.0);
#pragma unroll
      for (int o = 32; o; o >>= 1) cs += __shfl_xor(cs, o, 64);
      if (lane == 0) wred[wv] = cs;
    }
    // ---- zero next step's B buffer slice (atomic stores) ----
    {
      double* Bz = Bbuf + (size_t)((t + 1) % 3) * NB * NP1 + (size_t)b * NP1;
      if (tid < 33) {
        const int j = s * 33 + tid;
        if (j < NP1) __hip_atomic_store(&Bz[j], 0.0, __ATOMIC_RELAXED, __HIP_MEMORY_SCOPE_AGENT);
      }
    }
    // ---- part init: dustbin-row contribution r_N*dv to every column ----
    {
      const float pinit = desig ? rN_sh * dv : 0.0f;
      for (int j = tid; j < LDP; j += 512) part[j] = pinit;
    }
    __syncthreads();

    // ---- fused: row dots (f64) + column partials (f32), from LDS ----
    const float cN = c_f[NN];
    double dot0 = 0.0, dot1 = 0.0, dot2 = 0.0, dot3 = 0.0;
    float4 pacc[4];
#pragma unroll
    for (int k = 0; k < 4; ++k) { pacc[k].x = 0.f; pacc[k].y = 0.f; pacc[k].z = 0.f; pacc[k].w = 0.f; }
#pragma unroll
    for (int k = 0; k < 4; ++k) {
      const int j4 = (lane << 2) + (k << 8);
      const float4 cc = *(const float4*)&c_f[j4];
      const double c0 = cc.x, c1 = cc.y, c2 = cc.z, c3 = cc.w;
#pragma unroll
      for (int q = 0; q < 4; ++q) {
        const float4 v = *(const float4*)&P0s[wrow + q][j4];
        const double dd = (double)v.x * c0 + (double)v.y * c1 +
                          (double)v.z * c2 + (double)v.w * c3;
        if (q == 0) dot0 += dd; else if (q == 1) dot1 += dd;
        else if (q == 2) dot2 += dd; else dot3 += dd;
        pacc[k].x = fmaf(r4[q], v.x, pacc[k].x);
        pacc[k].y = fmaf(r4[q], v.y, pacc[k].y);
        pacc[k].z = fmaf(r4[q], v.z, pacc[k].z);
        pacc[k].w = fmaf(r4[q], v.w, pacc[k].w);
      }
    }
    float ptail = 0.f;
    if (lane == 0) {
#pragma unroll
      for (int q = 0; q < 4; ++q) {
        const float vN = P0s[wrow + q][NN];
        const double dd = (double)vN * (double)cN;
        if (q == 0) dot0 += dd; else if (q == 1) dot1 += dd;
        else if (q == 2) dot2 += dd; else dot3 += dd;
        ptail = fmaf(r4[q], vN, ptail);
      }
    }
#pragma unroll
    for (int o = 32; o; o >>= 1) {
      dot0 += __shfl_xor(dot0, o, 64);
      dot1 += __shfl_xor(dot1, o, 64);
      dot2 += __shfl_xor(dot2, o, 64);
      dot3 += __shfl_xor(dot3, o, 64);
    }
    // r_{t+1} for this wave's rows (part above used OLD r4)
    r4[0] = (float)(1.0 / dot0);
    r4[1] = (float)(1.0 / dot1);
    r4[2] = (float)(1.0 / dot2);
    r4[3] = (float)(1.0 / dot3);
    // combine column partials across waves
#pragma unroll
    for (int k = 0; k < 4; ++k) {
      const int j4 = (lane << 2) + (k << 8);
      atomicAdd(&part[j4 + 0], pacc[k].x);
      atomicAdd(&part[j4 + 1], pacc[k].y);
      atomicAdd(&part[j4 + 2], pacc[k].z);
      atomicAdd(&part[j4 + 3], pacc[k].w);
    }
    if (lane == 0) atomicAdd(&part[NN], ptail);
    // dustbin row update: u_N = dv * sum(c); r_N' = N / u_N
    if (desig && tid == 0) {
      const double sumc = ((wred[0] + wred[1]) + (wred[2] + wred[3])) +
                          ((wred[4] + wred[5]) + (wred[6] + wred[7]));
      rN_sh = (float)((double)NN / ((double)dv * sumc));
    }
    __syncthreads();
    // ---- global B accumulation (f64 atomics, device scope) ----
    for (int j = tid; j < NP1; j += 512)
      atomicAdd(&Bacc[j], (double)part[j]);
    // ---- per-batch barrier (32 arrivals), release/acquire ----
    if (t < NSTEPS - 1) {
      __syncthreads();  // drain all threads' atomics (vmcnt(0) before s_barrier)
      if (tid == 0) {
        __hip_atomic_fetch_add(&ctr[t * 8 + b], 1u, __ATOMIC_RELEASE, __HIP_MEMORY_SCOPE_AGENT);
        unsigned v = 0; int guard = 0;
        do {
          v = __hip_atomic_load(&ctr[t * 8 + b], __ATOMIC_ACQUIRE, __HIP_MEMORY_SCOPE_AGENT);
          if (v >= 32u) break;
          __builtin_amdgcn_s_sleep(1);
        } while (++guard < (1 << 20));
      }
      __syncthreads();
    }
  }
  // ---- write final r (r_100) ----
  if (lane == 0) {
    float* ro = rfin + b * NP1;
#pragma unroll
    for (int q = 0; q < 4; ++q) ro[row0 + wrow + q] = r4[q];
  }
  if (desig && tid == 0) rfin[b * NP1 + NN] = rN_sh;
}

// ----------------------------------------------------- final c from B ------
__global__ __launch_bounds__(256) void cfinal_kernel(const double* __restrict__ Bfin,
                                                     float* __restrict__ cfin) {
  const int b = blockIdx.x;
  for (int j = threadIdx.x; j < NP1; j += 256)
    cfin[b * LDP + j] = (float)(((j == NN) ? (double)NN : 1.0) / Bfin[b * NP1 + j]);
}

// --------------------------------------------------------------- finalize --
__global__ __launch_bounds__(256) void finalize_kernel(const float* __restrict__ P0,
                                                       float* __restrict__ Pout,
                                                       const float* __restrict__ rfin,
                                                       const float* __restrict__ cfin) {
  const int bi = blockIdx.x;
  const int b = bi & 7, i = bi >> 3;
  const int tid = threadIdx.x;
  const float rv = rfin[b * NP1 + i];
  const float4* src = (const float4*)(P0 + (size_t)b * NP1 * LDP + (size_t)i * LDP);
  const float4* cv = (const float4*)(cfin + b * LDP);
  float* dst = Pout + (size_t)b * NP1 * NP1 + (size_t)i * NP1;
  const float4 p = src[tid];
  const float4 c = cv[tid];
  dst[tid * 4 + 0] = rv * p.x * c.x;
  dst[tid * 4 + 1] = rv * p.y * c.y;
  dst[tid * 4 + 2] = rv * p.z * c.z;
  dst[tid * 4 + 3] = rv * p.w * c.w;
  if (tid == 0)
    dst[NN] = rv * ((const float*)src)[NN] * cfin[b * LDP + NN];
}

// ---------------------------------------------------------------------------
extern "C" void kernel_launch(void* const* d_in, const int* in_sizes, int n_in,
                              void* d_out, int out_size, void* d_ws, size_t ws_size,
                              hipStream_t stream) {
  const float* fA = (const float*)d_in[0];
  const float* fB = (const float*)d_in[1];
  const float* dustbin = (const float*)d_in[2];

  float* Pout = (float*)d_out;

  float* P0 = (float*)d_ws;                      // [8][1025][1028] f32
  float* rfin = P0 + (size_t)NB * NP1 * LDP;     // [8][1025] f32
  float* cfin = rfin + NB * NP1;                 // [8][1028] f32
  double* Bbuf = (double*)(((uintptr_t)(cfin + NB * LDP) + 15) & ~(uintptr_t)15);  // [3][8][1025] f64
  double* partZ = Bbuf + 3 * NB * NP1;           // [8][256] f64
  float* rinit = (float*)(partZ + NB * 256);     // [8] f32
  unsigned* ctr = (unsigned*)(rinit + 8);        // [100][8] u32
  float* invA = (float*)(ctr + NSTEPS * 8);      // [8][1024]
  float* invB = invA + NB * NN;                  // [8][1024]

  norm_kernel<<<4096, 256, 0, stream>>>(fA, fB, invA, invB);
  gemm_exp_kernel<<<2048, 256, 0, stream>>>(fA, fB, invA, invB, P0, partZ);
  fill_dustbin_kernel<<<NB, 1024, 0, stream>>>(dustbin, P0);
  init2_kernel<<<NB, 256, 0, stream>>>(partZ, rinit, Bbuf, ctr);

  void* args[] = {(void*)&P0, (void*)&dustbin, (void*)&rinit,
                  (void*)&Bbuf, (void*)&ctr, (void*)&rfin};
  hipLaunchCooperativeKernel((const void*)sinkhorn_persist, dim3(256), dim3(512),
                             args, 0, stream);

  // after t=99: B_99 (col sums) in Bbuf[99%3=0]
  cfinal_kernel<<<NB, 256, 0, stream>>>(Bbuf, cfin);
  finalize_kernel<<<NB * NP1, 256, 0, stream>>>(P0, Pout, rfin, cfin);
}

// Round 9
// 994.047 us; speedup vs baseline: 2.1870x; 2.1870x over previous
//
#include <hip/hip_runtime.h>
#include <math.h>
#include <stdint.h>

#define NB 8
#define NN 1024
#define DD 256
#define NP1 1025
#define LDC 1028   // cfin row stride (floats)
#define NSTEPS 100

// ---------------------------------------------------------------- norms ----
__global__ __launch_bounds__(256) void norm_kernel(const float* __restrict__ fA,
                                                   const float* __restrict__ fB,
                                                   float* __restrict__ invA,
                                                   float* __restrict__ invB) {
  int gw = (blockIdx.x * 256 + threadIdx.x) >> 6;  // global wave id, 0..16383
  int lane = threadIdx.x & 63;
  const float* src;
  float* dst;
  int row;
  if (gw < NB * NN) { src = fA; dst = invA; row = gw; }
  else              { src = fB; dst = invB; row = gw - NB * NN; }
  float4 v = *(const float4*)(src + (size_t)row * DD + lane * 4);
  double ss = (double)v.x * v.x + (double)v.y * v.y + (double)v.z * v.z + (double)v.w * v.w;
#pragma unroll
  for (int o = 32; o; o >>= 1) ss += __shfl_xor(ss, o, 64);
  if (lane == 0) dst[row] = (float)(1.0 / sqrt(fmax(ss, 1e-12)));
}

// ------------------------------------------------ GEMM + exp + partial Z ---
// Stores ONLY the 1024x1024 body (stride 1024); dustbin handled analytically.
__global__ __launch_bounds__(256) void gemm_exp_kernel(const float* __restrict__ fA,
                                                       const float* __restrict__ fB,
                                                       const float* __restrict__ invA,
                                                       const float* __restrict__ invB,
                                                       float* __restrict__ P0,
                                                       double* __restrict__ partZ) {
  const int id = blockIdx.x;
  const int b = id & 7;
  const int tile = id >> 3;
  const int bx = tile & 15, by = tile >> 4;
  const int row0 = by * 64, col0 = bx * 64;
  const int tid = threadIdx.x;
  const int tx = tid & 15, ty = tid >> 4;
  __shared__ __align__(16) float As[16][68];
  __shared__ __align__(16) float Bs[16][68];
  __shared__ double zred[256];
  float acc[4][4] = {{0.f}};
  const int lm = tid >> 2, kq = (tid & 3) << 2;
  const float sa = invA[b * NN + row0 + lm];
  const float sb = invB[b * NN + col0 + lm];
  const float* pA = fA + (size_t)(b * NN + row0 + lm) * DD + kq;
  const float* pB = fB + (size_t)(b * NN + col0 + lm) * DD + kq;
  for (int k0 = 0; k0 < DD; k0 += 16) {
    const float4 a4 = *(const float4*)(pA + k0);
    const float4 b4 = *(const float4*)(pB + k0);
    As[kq + 0][lm] = a4.x * sa; As[kq + 1][lm] = a4.y * sa;
    As[kq + 2][lm] = a4.z * sa; As[kq + 3][lm] = a4.w * sa;
    Bs[kq + 0][lm] = b4.x * sb; Bs[kq + 1][lm] = b4.y * sb;
    Bs[kq + 2][lm] = b4.z * sb; Bs[kq + 3][lm] = b4.w * sb;
    __syncthreads();
#pragma unroll
    for (int kk = 0; kk < 16; ++kk) {
      const float4 av = *(const float4*)&As[kk][ty * 4];
      const float4 bv = *(const float4*)&Bs[kk][tx * 4];
      const float ar[4] = {av.x, av.y, av.z, av.w};
      const float br[4] = {bv.x, bv.y, bv.z, bv.w};
#pragma unroll
      for (int a = 0; a < 4; ++a)
#pragma unroll
        for (int e = 0; e < 4; ++e)
          acc[a][e] = fmaf(ar[a], br[e], acc[a][e]);
    }
    __syncthreads();
  }
  // exp(5*clip(S,-3,3)) == exp(-5*clip(-S,-3,3))  (matches reference exactly)
  double zs = 0.0;
#pragma unroll
  for (int a = 0; a < 4; ++a)
#pragma unroll
    for (int e = 0; e < 4; ++e) {
      const float S = acc[a][e];
      const float C = fminf(fmaxf(-S, -3.0f), 3.0f);
      const float p = expf(-5.0f * C);
      acc[a][e] = p;
      zs += (double)p;
    }
  {
    float* P0b = P0 + (size_t)b * NN * NN;
#pragma unroll
    for (int a = 0; a < 4; ++a) {
      float4 v;
      v.x = acc[a][0]; v.y = acc[a][1]; v.z = acc[a][2]; v.w = acc[a][3];
      *(float4*)(P0b + (size_t)(row0 + ty * 4 + a) * NN + col0 + tx * 4) = v;
    }
  }
  zred[tid] = zs;
  __syncthreads();
#pragma unroll
  for (int o = 128; o; o >>= 1) {
    if (tid < o) zred[tid] += zred[tid + o];
    __syncthreads();
  }
  if (tid == 0) partZ[(b * 16 + by) * 16 + bx] = zred[0];
}

// ------------------------------------------------------- init r0, B bufs ---
// Z from body only (scale of r0 is transient: Sinkhorn fixed point is
// invariant to it -- proven passing since R5).
__global__ __launch_bounds__(256) void init_rc_kernel(const double* __restrict__ partZ,
                                                      float* __restrict__ r0,
                                                      double* __restrict__ Binit,
                                                      double* __restrict__ Bzero) {
  const int b = blockIdx.x, tid = threadIdx.x;
  __shared__ double red[256];
  red[tid] = partZ[b * 256 + tid];
  __syncthreads();
#pragma unroll
  for (int o = 128; o; o >>= 1) {
    if (tid < o) red[tid] += red[tid + o];
    __syncthreads();
  }
  const double Z = red[0];
  const float rv = (float)(1.0 / Z);
  for (int i = tid; i < NP1; i += 256) {
    r0[b * NP1 + i] = rv;
    Binit[b * NP1 + i] = (i == NN) ? (double)NN : 1.0;  // so c_0 = ab/Binit = 1
    Bzero[b * NP1 + i] = 0.0;
  }
}

// --------------------------------------------- one Sinkhorn step kernel ----
// Body-only P0 (1024x1024, per-batch 4.0 MiB -> fits XCD L2, b = id%8 pin).
//   u_i = body_i . c + dv*c_N          -> r'_i = 1/u_i
//   u_N = dv*(sum(c)+c_N)              -> r'_N = N/u_N        (desig block)
//   B_j = colsum(r .* body)_j + r_N*dv (desig adds the r_N*dv term)
//   B_N = dv*(sum(r) + r_N)            (per-block f64 partials)
// 512 blocks x 512 thr: slab = id/8 (16 rows), 8 waves x 2 rows, float4
// staged, loads issued before the prologue.
__global__ __launch_bounds__(512, 4) void step_kernel(const float* __restrict__ P0,
                                                      const float* __restrict__ dustbin,
                                                      const float* __restrict__ rin,
                                                      float* __restrict__ rout,
                                                      const double* __restrict__ Bprev,
                                                      double* __restrict__ Bacc,
                                                      double* __restrict__ Bzero) {
  const int id = blockIdx.x;
  const int b = id & 7;   // XCD pin: batch = bid % 8
  const int s = id >> 3;  // slab 0..63
  const int tid = threadIdx.x;
  const int lane = tid & 63;
  const int wv = tid >> 6;  // 0..7
  const bool desig = (s == 63);

  __shared__ __align__(16) float c_f[NN];
  __shared__ __align__(16) float part_lds[8][NN];
  __shared__ double wredR[8];
  __shared__ double wredC[8];
  __shared__ double cN_sh;

  const float d = dustbin[0];
  const float dv = expf(-5.0f * fminf(fmaxf(-d, -3.0f), 3.0f));
  const double dv_d = (double)dv;

  const float* P0b = P0 + (size_t)b * NN * NN;
  const float* rv_in = rin + b * NP1;
  const int rowA = s * 16 + wv;
  const int rowB = rowA + 8;
  const float wA = rv_in[rowA];
  const float wB = rv_in[rowB];
  const float4* pA4 = (const float4*)(P0b + (size_t)rowA * NN);
  const float4* pB4 = (const float4*)(P0b + (size_t)rowB * NN);

  // ---- issue all row loads first (latency hides under prologue) ----
  float4 a4[4], b4[4];
#pragma unroll
  for (int k = 0; k < 4; ++k) {
    a4[k] = pA4[lane + (k << 6)];
    b4[k] = pB4[lane + (k << 6)];
  }

  // ---- prologue: zero next-step B (512x17 = 8704 >= 8200); c = ab/Bprev ----
  if (tid < 17) {
    const int idx = id * 17 + tid;
    if (idx < NB * NP1) Bzero[idx] = 0.0;
  }
  const double* Bp = Bprev + b * NP1;
  for (int j = tid; j < NN; j += 512) c_f[j] = (float)(1.0 / Bp[j]);
  if (tid == 0) cN_sh = (double)NN / Bp[NN];
  __syncthreads();
  const double cN = cN_sh;

  // ---- fused: row dots (f64) + column partials (f32) ----
  double dotA = 0.0, dotB = 0.0;
  float4 pk[4];
#pragma unroll
  for (int k = 0; k < 4; ++k) {
    const int j4 = lane + (k << 6);
    const float4 cc = ((const float4*)c_f)[j4];
    dotA += (double)a4[k].x * (double)cc.x + (double)a4[k].y * (double)cc.y +
            (double)a4[k].z * (double)cc.z + (double)a4[k].w * (double)cc.w;
    dotB += (double)b4[k].x * (double)cc.x + (double)b4[k].y * (double)cc.y +
            (double)b4[k].z * (double)cc.z + (double)b4[k].w * (double)cc.w;
    pk[k].x = fmaf(wA, a4[k].x, wB * b4[k].x);
    pk[k].y = fmaf(wA, a4[k].y, wB * b4[k].y);
    pk[k].z = fmaf(wA, a4[k].z, wB * b4[k].z);
    pk[k].w = fmaf(wA, a4[k].w, wB * b4[k].w);
  }
#pragma unroll
  for (int o = 32; o; o >>= 1) {
    dotA += __shfl_xor(dotA, o, 64);
    dotB += __shfl_xor(dotB, o, 64);
  }
  dotA += dv_d * cN;  // dustbin-column term (post-reduce: added once)
  dotB += dv_d * cN;
  if (lane == 0) {
    float* ro = rout + b * NP1;
    ro[rowA] = (float)(1.0 / dotA);
    ro[rowB] = (float)(1.0 / dotB);
    wredR[wv] = (double)wA + (double)wB;  // old r values, for B_N
  }
  // per-wave column partials to LDS
  {
    float4* pl4 = (float4*)&part_lds[wv][0];
#pragma unroll
    for (int k = 0; k < 4; ++k) pl4[lane + (k << 6)] = pk[k];
  }
  // block sum(c) in f64 (each thread sums exactly the 2 c's it wrote)
  {
    double cs = (double)c_f[tid] + (double)c_f[tid + 512];
#pragma unroll
    for (int o = 32; o; o >>= 1) cs += __shfl_xor(cs, o, 64);
    if (lane == 0) wredC[wv] = cs;
  }
  __syncthreads();

  // ---- combine partials; one f64 atomic per column ----
  const float rN = rv_in[NN];
  const float rNdv = rN * dv;
  double* Ba = Bacc + b * NP1;
  for (int j = tid; j < NN; j += 512) {
    float s0 = ((part_lds[0][j] + part_lds[1][j]) + (part_lds[2][j] + part_lds[3][j])) +
               ((part_lds[4][j] + part_lds[5][j]) + (part_lds[6][j] + part_lds[7][j]));
    if (desig) s0 += rNdv;  // dustbin-row contribution, added once per batch
    atomicAdd(Ba + j, (double)s0);
  }
  if (tid == 0) {
    double rsum = ((wredR[0] + wredR[1]) + (wredR[2] + wredR[3])) +
                  ((wredR[4] + wredR[5]) + (wredR[6] + wredR[7]));
    if (desig) rsum += (double)rN;
    atomicAdd(Ba + NN, dv_d * rsum);  // B_N = dv * sum(r)
    if (desig) {
      const double sc = ((wredC[0] + wredC[1]) + (wredC[2] + wredC[3])) +
                        ((wredC[4] + wredC[5]) + (wredC[6] + wredC[7])) + cN;
      rout[b * NP1 + NN] = (float)((double)NN / (dv_d * sc));  // r'_N
    }
  }
}

// ----------------------------------------------------- final c from B ------
__global__ __launch_bounds__(256) void cfinal_kernel(const double* __restrict__ Bfin,
                                                     float* __restrict__ cfin) {
  const int b = blockIdx.x;
  for (int j = threadIdx.x; j < NP1; j += 256)
    cfin[b * LDC + j] = (float)(((j == NN) ? (double)NN : 1.0) / Bfin[b * NP1 + j]);
}

// --------------------------------------------------------------- finalize --
// One row per block; body rows from ws (stride 1024), dustbin row/col = dv.
__global__ __launch_bounds__(256) void finalize_kernel(const float* __restrict__ P0,
                                                       const float* __restrict__ dustbin,
                                                       float* __restrict__ Pout,
                                                       const float* __restrict__ rfin,
                                                       const float* __restrict__ cfin) {
  const int bi = blockIdx.x;
  const int b = bi & 7, i = bi >> 3;  // XCD pin
  const int tid = threadIdx.x;
  const float d = dustbin[0];
  const float dv = expf(-5.0f * fminf(fmaxf(-d, -3.0f), 3.0f));
  const float4* cv = (const float4*)(cfin + b * LDC);
  const float cN = cfin[b * LDC + NN];
  float* dst = Pout + (size_t)b * NP1 * NP1 + (size_t)i * NP1;
  const float4 c = cv[tid];
  if (i < NN) {
    const float rv = rfin[b * NP1 + i];
    const float4 p = ((const float4*)(P0 + ((size_t)b * NN + i) * NN))[tid];
    dst[tid * 4 + 0] = rv * p.x * c.x;
    dst[tid * 4 + 1] = rv * p.y * c.y;
    dst[tid * 4 + 2] = rv * p.z * c.z;
    dst[tid * 4 + 3] = rv * p.w * c.w;
    if (tid == 0) dst[NN] = rv * dv * cN;
  } else {
    const float rv = rfin[b * NP1 + NN];
    dst[tid * 4 + 0] = rv * dv * c.x;
    dst[tid * 4 + 1] = rv * dv * c.y;
    dst[tid * 4 + 2] = rv * dv * c.z;
    dst[tid * 4 + 3] = rv * dv * c.w;
    if (tid == 0) dst[NN] = rv * dv * cN;
  }
}

// ---------------------------------------------------------------------------
extern "C" void kernel_launch(void* const* d_in, const int* in_sizes, int n_in,
                              void* d_out, int out_size, void* d_ws, size_t ws_size,
                              hipStream_t stream) {
  const float* fA = (const float*)d_in[0];
  const float* fB = (const float*)d_in[1];
  const float* dustbin = (const float*)d_in[2];

  float* Pout = (float*)d_out;

  float* P0 = (float*)d_ws;                    // [8][1024][1024] f32 body (32 MiB)
  float* rbuf = P0 + (size_t)NB * NN * NN;     // [2][8][1025] f32
  float* cfin = rbuf + 2 * NB * NP1;           // [8][1028] f32
  double* Bbuf = (double*)(((uintptr_t)(cfin + NB * LDC) + 15) & ~(uintptr_t)15);  // [3][8][1025] f64
  double* partZ = Bbuf + 3 * NB * NP1;         // [8][256] f64
  float* invA = (float*)(partZ + NB * 256);    // [8][1024]
  float* invB = invA + NB * NN;                // [8][1024]

  norm_kernel<<<4096, 256, 0, stream>>>(fA, fB, invA, invB);
  gemm_exp_kernel<<<2048, 256, 0, stream>>>(fA, fB, invA, invB, P0, partZ);
  // r_0 -> rbuf[0]; B "prev" for t=0 -> Bbuf[2] (c_0 = 1); zero Bbuf[0]
  init_rc_kernel<<<NB, 256, 0, stream>>>(partZ, rbuf, Bbuf + 2 * NB * NP1, Bbuf);

  // step t: reads r[t%2], B[(t+2)%3]; writes r[(t+1)%2]; accumulates B[t%3];
  //         zeroes B[(t+1)%3] (for step t+1).
  for (int t = 0; t < NSTEPS; ++t) {
    float* rin = rbuf + (t & 1) * NB * NP1;
    float* rout = rbuf + ((t + 1) & 1) * NB * NP1;
    double* Bprev = Bbuf + ((t + 2) % 3) * NB * NP1;
    double* Bacc = Bbuf + (t % 3) * NB * NP1;
    double* Bzero = Bbuf + ((t + 1) % 3) * NB * NP1;
    step_kernel<<<512, 512, 0, stream>>>(P0, dustbin, rin, rout, Bprev, Bacc, Bzero);
  }

  // after t=99: r_100 in rbuf[0]; B_99 (col sums) in Bbuf[99%3=0]
  cfinal_kernel<<<NB, 256, 0, stream>>>(Bbuf, cfin);
  finalize_kernel<<<NB * NP1, 256, 0, stream>>>(P0, dustbin, Pout, rbuf, cfin);
}